// Round 1
// 690.838 us; speedup vs baseline: 1.2579x; 1.2579x over previous
//
#include <hip/hip_runtime.h>
#include <math.h>

#define RTOT   196608   // B*T*N rows
#define NNODE  1024
#define NBT    192      // B*T

typedef __attribute__((ext_vector_type(8))) short short8;
typedef __attribute__((ext_vector_type(4))) float f32x4;

__device__ __forceinline__ unsigned short f2bf(float f) {
  unsigned u = __float_as_uint(f);
  return (unsigned short)((u + 0x7fffu + ((u >> 16) & 1u)) >> 16);
}
__device__ __forceinline__ float bf2f(unsigned short b) {
  return __uint_as_float(((unsigned)b) << 16);
}

// ---------------- prep kernels ----------------
__global__ __launch_bounds__(256) void pos_kernel(
    const float* __restrict__ eigvec, const float* __restrict__ eigval,
    float* __restrict__ pos) {
  int i = blockIdx.x * 256 + threadIdx.x;      // < 1024*128
  int d = i >> 10, n = i & 1023;
  pos[n * 128 + d] = eigvec[d * 1024 + n] * eigval[d];
}

// transpose + bf16-ify 6 [128][128] weights -> [w][col][k] bf16
__global__ __launch_bounds__(256) void prepw_kernel(
    const float* __restrict__ W0, const float* __restrict__ W1,
    const float* __restrict__ W2, const float* __restrict__ W3,
    const float* __restrict__ W4, const float* __restrict__ W5,
    unsigned short* __restrict__ out) {
  int i = blockIdx.x * 256 + threadIdx.x;      // < 6*16384
  int wsel = i >> 14, rem = i & 16383, c = rem >> 7, k = rem & 127;
  const float* W = (wsel == 0) ? W0 : (wsel == 1) ? W1 : (wsel == 2) ? W2
                 : (wsel == 3) ? W3 : (wsel == 4) ? W4 : W5;
  out[i] = f2bf(W[k * 128 + c]);
}

// folded score weights: Wcomb[k][m] = Wq[k]·embQ[m] + Wk[k]·embK[m]  (fp32)
//                       bcomb[m]    = bq·embQ[m] + bk·embK[m]
__global__ __launch_bounds__(256) void wcomb_kernel(
    const float* __restrict__ Wq, const float* __restrict__ Wk,
    const float* __restrict__ bq, const float* __restrict__ bk,
    const float* __restrict__ emb, float* __restrict__ Wcomb,
    float* __restrict__ bcomb) {
  int i = blockIdx.x * 256 + threadIdx.x;      // 8192 Wcomb + 64 bias
  if (i < 8192) {
    int k = i >> 6, m = i & 63;
    float s = 0.f;
    for (int d = 0; d < 128; ++d)
      s += Wq[k * 128 + d] * emb[m * 256 + d]
         + Wk[k * 128 + d] * emb[m * 256 + 128 + d];
    Wcomb[i] = s;
  } else if (i < 8256) {
    int m = i - 8192;
    float s = 0.f;
    for (int d = 0; d < 128; ++d)
      s += bq[d] * emb[m * 256 + d] + bk[d] * emb[m * 256 + 128 + d];
    bcomb[m] = s;
  }
}

// ---------------- generic 128-row-tile fp32 GEMM (score-critical path) ------
template<int NCOL, int KCHUNKS, int ADDPOS, int HASBIAS, int WRITEXB>
__global__ __launch_bounds__(256, 2) void gemm_k(
    const float* __restrict__ A1, const float* __restrict__ A2,
    const float* __restrict__ W, const float* __restrict__ bias,
    const float* __restrict__ pos, unsigned short* __restrict__ xb,
    float* __restrict__ out) {
  __shared__ float As[128 * 64];          // [m][k], 32 KB
  __shared__ float Ws[64 * NCOL];
  constexpr int JW = (NCOL == 128) ? 2 : 1;
  const int tid = threadIdx.x;
  const int tx = tid & 15, ty = tid >> 4;
  const int row0 = blockIdx.x * 128;

  float acc[8][4 * JW];
#pragma unroll
  for (int i = 0; i < 8; ++i)
#pragma unroll
    for (int j = 0; j < 4 * JW; ++j) acc[i][j] = 0.f;

  for (int kc = 0; kc < KCHUNKS; ++kc) {
    const int kt = kc * 64;
    const float* __restrict__ Asrc = (kt < 128) ? A1 : A2;
    const int kbase = kt & 127;
#pragma unroll
    for (int i = 0; i < 8; ++i) {
      int f = tid + 256 * i;
      int m = f >> 4;
      int k4 = (f & 15) << 2;
      int r = row0 + m;
      float4 a = *(const float4*)&Asrc[(size_t)r * 128 + kbase + k4];
      if constexpr (ADDPOS) {
        float4 p = *(const float4*)&pos[(r & 1023) * 128 + kbase + k4];
        a.x += p.x; a.y += p.y; a.z += p.z; a.w += p.w;
      }
      if constexpr (WRITEXB) {
        unsigned lo = (unsigned)f2bf(a.x) | ((unsigned)f2bf(a.y) << 16);
        unsigned hi = (unsigned)f2bf(a.z) | ((unsigned)f2bf(a.w) << 16);
        *(uint2*)&xb[(size_t)r * 128 + kbase + k4] = make_uint2(lo, hi);
      }
      *(float4*)&As[m * 64 + k4] = a;
    }
#pragma unroll
    for (int i = 0; i < NCOL / 16; ++i) {
      int f = tid + 256 * i;
      int kk = f / (NCOL / 4);
      int c4 = (f % (NCOL / 4)) << 2;
      *(float4*)&Ws[kk * NCOL + c4] =
          *(const float4*)&W[(size_t)(kt + kk) * NCOL + c4];
    }
    __syncthreads();
    for (int k4 = 0; k4 < 64; k4 += 4) {
      float a[8][4];
#pragma unroll
      for (int i = 0; i < 8; ++i)
        *(float4*)&a[i][0] = *(const float4*)&As[(ty * 8 + i) * 64 + k4];
#pragma unroll
      for (int kk = 0; kk < 4; ++kk) {
        float4 w0 = *(const float4*)&Ws[(k4 + kk) * NCOL + tx * 4];
        float4 w1;
        if constexpr (JW == 2)
          w1 = *(const float4*)&Ws[(k4 + kk) * NCOL + 64 + tx * 4];
#pragma unroll
        for (int i = 0; i < 8; ++i) {
          float av = a[i][kk];
          acc[i][0] = fmaf(av, w0.x, acc[i][0]);
          acc[i][1] = fmaf(av, w0.y, acc[i][1]);
          acc[i][2] = fmaf(av, w0.z, acc[i][2]);
          acc[i][3] = fmaf(av, w0.w, acc[i][3]);
          if constexpr (JW == 2) {
            acc[i][4] = fmaf(av, w1.x, acc[i][4]);
            acc[i][5] = fmaf(av, w1.y, acc[i][5]);
            acc[i][6] = fmaf(av, w1.z, acc[i][6]);
            acc[i][7] = fmaf(av, w1.w, acc[i][7]);
          }
        }
      }
    }
    __syncthreads();
  }
  float4 b0 = make_float4(0.f, 0.f, 0.f, 0.f);
  float4 b1 = make_float4(0.f, 0.f, 0.f, 0.f);
  if constexpr (HASBIAS) {
    b0 = *(const float4*)&bias[tx * 4];
    if constexpr (JW == 2) b1 = *(const float4*)&bias[64 + tx * 4];
  }
#pragma unroll
  for (int i = 0; i < 8; ++i) {
    const int r = row0 + ty * 8 + i;
    {
      float4 o = make_float4(acc[i][0] + b0.x, acc[i][1] + b0.y,
                             acc[i][2] + b0.z, acc[i][3] + b0.w);
      *(float4*)&out[(size_t)r * NCOL + tx * 4] = o;
    }
    if constexpr (JW == 2) {
      float4 o = make_float4(acc[i][4] + b1.x, acc[i][5] + b1.y,
                             acc[i][6] + b1.z, acc[i][7] + b1.w);
      *(float4*)&out[(size_t)r * NCOL + 64 + tx * 4] = o;
    }
  }
}

// ---------------- bf16 MFMA GEMM, 128x128 tile, K=128 -----------------------
// EPI: 0 = bias, fp32 out (Q/K/V)
//      1 = bias + (x+pos) resid + LN, bf16 out (Wo -> vln)
//      2 = bias + relu, bf16 out (FF1 -> h1)
//      3 = bias + bf16 resid + LN, fp32 out (FF2 -> final)
template<int EPI>
__global__ __launch_bounds__(256, 2) void gemm_mfma(
    const unsigned short* __restrict__ A, const unsigned short* __restrict__ Bt,
    const float* __restrict__ bias, const float* __restrict__ x,
    const float* __restrict__ pos, const unsigned short* __restrict__ resb,
    float* __restrict__ outf, unsigned short* __restrict__ outb) {
  __shared__ float lds_s[128][2];
  __shared__ float lds_q[128][2];
  const int tid = threadIdx.x;
  const int w = tid >> 6, lane = tid & 63;
  const int wr = w >> 1, wc = w & 1;
  const int lhi = lane >> 4, llo = lane & 15;
  const int r0 = blockIdx.x * 128;

  // hold all B fragments for this wave's 64 cols (K=128): 64 VGPRs
  short8 bf[4][4];
#pragma unroll
  for (int j = 0; j < 4; ++j)
#pragma unroll
    for (int kq = 0; kq < 4; ++kq)
      bf[j][kq] = *(const short8*)&Bt[(size_t)(wc * 64 + j * 16 + llo) * 128 +
                                      kq * 32 + lhi * 8];
  f32x4 acc[4][4];
#pragma unroll
  for (int i = 0; i < 4; ++i)
#pragma unroll
    for (int j = 0; j < 4; ++j) acc[i][j] = (f32x4)(0.0f);

#pragma unroll
  for (int i = 0; i < 4; ++i) {
    short8 af[4];
#pragma unroll
    for (int kq = 0; kq < 4; ++kq)
      af[kq] = *(const short8*)&A[(size_t)(r0 + wr * 64 + i * 16 + llo) * 128 +
                                  kq * 32 + lhi * 8];
#pragma unroll
    for (int kq = 0; kq < 4; ++kq)
#pragma unroll
      for (int j = 0; j < 4; ++j)
        acc[i][j] = __builtin_amdgcn_mfma_f32_16x16x32_bf16(
            af[kq], bf[j][kq], acc[i][j], 0, 0, 0);
  }

  float bvals[4];
#pragma unroll
  for (int j = 0; j < 4; ++j) bvals[j] = bias[wc * 64 + j * 16 + llo];

  if constexpr (EPI == 1 || EPI == 3) {
#pragma unroll
    for (int i = 0; i < 4; ++i) {
#pragma unroll
      for (int reg = 0; reg < 4; ++reg) {
        const int rl = wr * 64 + i * 16 + lhi * 4 + reg;
        const int r = r0 + rl;
        float s = 0.f, q = 0.f;
#pragma unroll
        for (int j = 0; j < 4; ++j) {
          const int c = wc * 64 + j * 16 + llo;
          float vv = acc[i][j][reg] + bvals[j];
          if constexpr (EPI == 1)
            vv += x[(size_t)r * 128 + c] + pos[(r & 1023) * 128 + c];
          else
            vv += bf2f(resb[(size_t)r * 128 + c]);
          acc[i][j][reg] = vv;
          s += vv; q += vv * vv;
        }
#pragma unroll
        for (int m = 1; m < 16; m <<= 1) {
          s += __shfl_xor(s, m);
          q += __shfl_xor(q, m);
        }
        if (llo == 0) { lds_s[rl][wc] = s; lds_q[rl][wc] = q; }
      }
    }
    __syncthreads();
#pragma unroll
    for (int i = 0; i < 4; ++i) {
#pragma unroll
      for (int reg = 0; reg < 4; ++reg) {
        const int rl = wr * 64 + i * 16 + lhi * 4 + reg;
        const int r = r0 + rl;
        float s = lds_s[rl][0] + lds_s[rl][1];
        float q = lds_q[rl][0] + lds_q[rl][1];
        float mu = s * (1.f / 128.f);
        float rstd = rsqrtf(q * (1.f / 128.f) - mu * mu + 1e-5f);
#pragma unroll
        for (int j = 0; j < 4; ++j) {
          const int c = wc * 64 + j * 16 + llo;
          float vv = (acc[i][j][reg] - mu) * rstd;
          if constexpr (EPI == 1)
            outb[(size_t)r * 128 + c] = f2bf(vv);
          else
            outf[(size_t)r * 128 + c] = vv;
        }
      }
    }
  } else {
#pragma unroll
    for (int i = 0; i < 4; ++i)
#pragma unroll
      for (int reg = 0; reg < 4; ++reg) {
        const int rl = wr * 64 + i * 16 + lhi * 4 + reg;
        const int r = r0 + rl;
#pragma unroll
        for (int j = 0; j < 4; ++j) {
          const int c = wc * 64 + j * 16 + llo;
          float vv = acc[i][j][reg] + bvals[j];
          if constexpr (EPI == 2) {
            vv = fmaxf(vv, 0.f);
            outb[(size_t)r * 128 + c] = f2bf(vv);
          } else {
            outf[(size_t)r * 128 + c] = vv;
          }
        }
      }
  }
}

// ---------------- top-16 per (bt, m) over 1024 scores ----------------
__global__ __launch_bounds__(256) void topk_kernel(
    const float* __restrict__ S, int* __restrict__ idx_out) {
  __shared__ float sc[8 * 1024];   // 32 KB
  const int tid = threadIdx.x;
  const int bt = blockIdx.x >> 3, mg = blockIdx.x & 7;
#pragma unroll
  for (int u = 0; u < 8; ++u) {
    int f = tid + 256 * u;         // < 2048
    int n = f >> 1, half = f & 1;
    float4 v = *(const float4*)&S[((size_t)bt * 1024 + n) * 64 + mg * 8 + half * 4];
    sc[(half * 4 + 0) * 1024 + n] = v.x;
    sc[(half * 4 + 1) * 1024 + n] = v.y;
    sc[(half * 4 + 2) * 1024 + n] = v.z;
    sc[(half * 4 + 3) * 1024 + n] = v.w;
  }
  __syncthreads();
  const int lane = tid & 63, w = tid >> 6;
  for (int ml = w * 2; ml < w * 2 + 2; ++ml) {
    float v[16];
#pragma unroll
    for (int q = 0; q < 4; ++q) {
      float4 t = *(const float4*)&sc[ml * 1024 + lane * 16 + q * 4];
      v[q * 4 + 0] = t.x; v[q * 4 + 1] = t.y;
      v[q * 4 + 2] = t.z; v[q * 4 + 3] = t.w;
    }
    const int outbase = (bt * 64 + mg * 8 + ml) << 4;
    for (int it = 0; it < 16; ++it) {
      float mv = v[0]; int li = 0;
#pragma unroll
      for (int u = 1; u < 16; ++u) {
        if (v[u] > mv) { mv = v[u]; li = u; }
      }
      int mi = (lane << 4) + li;
#pragma unroll
      for (int off = 1; off < 64; off <<= 1) {
        float ov = __shfl_xor(mv, off);
        int oi = __shfl_xor(mi, off);
        if (ov > mv || (ov == mv && oi < mi)) { mv = ov; mi = oi; }
      }
      bool mine = (mi >> 4) == lane;
      int rm = mi & 15;
#pragma unroll
      for (int u = 0; u < 16; ++u)
        if (mine && rm == u) v[u] = -3.402823466e38f;
      if (lane == 0) idx_out[outbase + it] = mi;
    }
  }
}

// ---------------- 16x16 attention, dense bf16 output ----------------
__global__ __launch_bounds__(256) void attn_dense(
    const float* __restrict__ Q, const float* __restrict__ K,
    const float* __restrict__ V, const int* __restrict__ idx,
    unsigned short* __restrict__ node_new) {
  __shared__ float sQ[16 * 132], sK[16 * 132], sV[16 * 132];
  __shared__ float sP[16 * 16];
  __shared__ int sidx[16];
  const int tid = threadIdx.x;
  const int bt = blockIdx.x >> 6, m = blockIdx.x & 63;
  if (tid < 16) sidx[tid] = idx[((bt * 64 + m) << 4) + tid];
  __syncthreads();
  const size_t base = (size_t)bt * 1024 * 128;
#pragma unroll
  for (int u = 0; u < 6; ++u) {
    int f = tid + 256 * u;         // < 1536
    int mat = f >> 9;
    int r = (f >> 5) & 15;
    int c4 = (f & 31) << 2;
    const float* src = (mat == 0) ? Q : (mat == 1) ? K : V;
    float* dst = (mat == 0) ? sQ : (mat == 1) ? sK : sV;
    *(float4*)&dst[r * 132 + c4] =
        *(const float4*)&src[base + (size_t)sidx[r] * 128 + c4];
  }
  __syncthreads();
  const int kk = tid >> 4, jj = tid & 15;
  float s = 0.f;
#pragma unroll
  for (int c4 = 0; c4 < 128; c4 += 4) {
    float4 q = *(const float4*)&sQ[kk * 132 + c4];
    float4 kv = *(const float4*)&sK[jj * 132 + c4];
    s = fmaf(q.x, kv.x, s); s = fmaf(q.y, kv.y, s);
    s = fmaf(q.z, kv.z, s); s = fmaf(q.w, kv.w, s);
  }
  s *= 0.08838834764831845f;       // 1/sqrt(128)
  float mx = s;
#pragma unroll
  for (int off = 8; off >= 1; off >>= 1) mx = fmaxf(mx, __shfl_xor(mx, off, 16));
  float e = expf(s - mx);
  float sum = e;
#pragma unroll
  for (int off = 8; off >= 1; off >>= 1) sum += __shfl_xor(sum, off, 16);
  sP[kk * 16 + jj] = e / sum;
  __syncthreads();
  const int dc = tid & 15;
  const int d0 = dc * 8;
  float o[8] = {0.f, 0.f, 0.f, 0.f, 0.f, 0.f, 0.f, 0.f};
#pragma unroll
  for (int j = 0; j < 16; ++j) {
    float p = sP[kk * 16 + j];
    float4 v0 = *(const float4*)&sV[j * 132 + d0];
    float4 v1 = *(const float4*)&sV[j * 132 + d0 + 4];
    o[0] = fmaf(p, v0.x, o[0]); o[1] = fmaf(p, v0.y, o[1]);
    o[2] = fmaf(p, v0.z, o[2]); o[3] = fmaf(p, v0.w, o[3]);
    o[4] = fmaf(p, v1.x, o[4]); o[5] = fmaf(p, v1.y, o[5]);
    o[6] = fmaf(p, v1.z, o[6]); o[7] = fmaf(p, v1.w, o[7]);
  }
  unsigned short* orow = node_new + base + (size_t)(m * 16 + kk) * 128 + d0;
  uint4 st;
  st.x = (unsigned)f2bf(o[0]) | ((unsigned)f2bf(o[1]) << 16);
  st.y = (unsigned)f2bf(o[2]) | ((unsigned)f2bf(o[3]) << 16);
  st.z = (unsigned)f2bf(o[4]) | ((unsigned)f2bf(o[5]) << 16);
  st.w = (unsigned)f2bf(o[6]) | ((unsigned)f2bf(o[7]) << 16);
  *(uint4*)orow = st;
}

// ---------------- invert idx_flat into per-node hit lists ----------------
__global__ __launch_bounds__(256) void build_lists(
    const int* __restrict__ idx, int* __restrict__ lists,
    int* __restrict__ counts) {
  int i = blockIdx.x * 256 + threadIdx.x;      // < 192*1024
  int bt = i >> 10, j = i & 1023;
  int n = idx[i];
  int slot = atomicAdd(&counts[bt * 1024 + n], 1);
  lists[(size_t)(bt * 1024 + n) * 64 + slot] = j;
}

// ---------------- gather-sum: dictb[bt][n] = bf16(sum(rows)/cnt) ------------
__global__ __launch_bounds__(256) void gather_sum(
    const unsigned short* __restrict__ node_new, const int* __restrict__ lists,
    const int* __restrict__ counts, unsigned short* __restrict__ outb) {
  const int lane = threadIdx.x & 63;
  const int row = blockIdx.x * 4 + (threadIdx.x >> 6);   // bt*1024+n
  const int cnt = counts[row];
  const int bt = row >> 10;
  const float inv = 1.0f / ((float)cnt + 1e-14f);
  const int* lp = lists + (size_t)row * 64;
  float ax = 0.f, ay = 0.f;
  for (int j = 0; j < cnt; ++j) {
    int src = lp[j];
    unsigned u = *(const unsigned*)&node_new[((size_t)bt * 1024 + src) * 128 + lane * 2];
    ax += bf2f(u & 0xffff); ay += bf2f(u >> 16);
  }
  ax *= inv; ay *= inv;
  unsigned pk = (unsigned)f2bf(ax) | ((unsigned)f2bf(ay) << 16);
  *(unsigned*)&outb[(size_t)row * 128 + lane * 2] = pk;
}

// ---------------- launch ----------------
extern "C" void kernel_launch(void* const* d_in, const int* in_sizes, int n_in,
                              void* d_out, int out_size, void* d_ws, size_t ws_size,
                              hipStream_t stream) {
  const float* x      = (const float*)d_in[0];
  const float* eigvec = (const float*)d_in[1];
  const float* eigval = (const float*)d_in[2];
  const float* Wq     = (const float*)d_in[3];
  const float* bq     = (const float*)d_in[4];
  const float* Wk     = (const float*)d_in[5];
  const float* bk     = (const float*)d_in[6];
  const float* Wv     = (const float*)d_in[7];
  const float* bv     = (const float*)d_in[8];
  const float* Wo     = (const float*)d_in[9];
  const float* bo     = (const float*)d_in[10];
  const float* nemb   = (const float*)d_in[11];
  const float* ffW1   = (const float*)d_in[12];
  const float* ffb1   = (const float*)d_in[13];
  const float* ffW2   = (const float*)d_in[14];
  const float* ffb2   = (const float*)d_in[15];
  float* outp = (float*)d_out;

  char* ws = (char*)d_ws;
  float*          pos    = (float*)(ws + 0);                  // 512 KB
  int*            idxp   = (int*)  (ws + 524288);             // 768 KB
  int*            counts = (int*)  (ws + 1310720);            // 768 KB
  // Wcomb/bcomb overlay counts: dead before counts memset (stream-ordered)
  float*          Wcomb  = (float*)(ws + 1310720);            // 32 KB
  float*          bcomb  = (float*)(ws + 1343488);            // 256 B
  unsigned short* Wtall  = (unsigned short*)(ws + 2097152);   // 192 KB (6 W^T bf16)
  unsigned short* xb     = (unsigned short*)(ws + 2293760);   // 48 MB: bf16(x+pos) -> vln
  float*          R1     = (float*)(ws + 52625408);           // 96 MB: K fp32 -> h1 bf16
  float*          R2     = (float*)(ws + 153288704);          // 96 MB: V fp32 -> lists
  float*          Sbuf   = (float*)(ws + 253952000);          // 48 MB: scores -> node_new bf16
  unsigned short* Wt_q = Wtall;
  unsigned short* Wt_k = Wtall + 16384;
  unsigned short* Wt_v = Wtall + 32768;
  unsigned short* Wt_o = Wtall + 49152;
  unsigned short* Wt_1 = Wtall + 65536;
  unsigned short* Wt_2 = Wtall + 81920;
  unsigned short* vln  = xb;                    // reuses xb after V-GEMM
  unsigned short* h1   = (unsigned short*)R1;   // reuses K after attn
  int*            lists = (int*)R2;             // reuses V after attn
  unsigned short* nnb  = (unsigned short*)Sbuf; // node_new bf16, after topk
  float*          Qbuf = outp;                  // Q in d_out until attn done
  unsigned short* dictb = (unsigned short*)d_out; // after gather (Q dead)

  pos_kernel<<<512, 256, 0, stream>>>(eigvec, eigval, pos);
  prepw_kernel<<<384, 256, 0, stream>>>(Wq, Wk, Wv, Wo, ffW1, ffW2, Wtall);
  wcomb_kernel<<<33, 256, 0, stream>>>(Wq, Wk, bq, bk, nemb, Wcomb, bcomb);

  // scores = (x+pos) @ Wcomb + bcomb  (fp32, top-k-critical path)
  // also emits xb = bf16(x+pos) for the MFMA GEMMs
  gemm_k<64, 2, 1, 1, 1><<<1536, 256, 0, stream>>>(
      x, nullptr, Wcomb, bcomb, pos, xb, Sbuf);
  topk_kernel<<<1536, 256, 0, stream>>>(Sbuf, idxp);

  // Q, K, V via bf16 MFMA (fp32 out) — only feed the 16x16 attention values
  gemm_mfma<0><<<1536, 256, 0, stream>>>(
      xb, Wt_q, bq, nullptr, nullptr, nullptr, Qbuf, nullptr);
  gemm_mfma<0><<<1536, 256, 0, stream>>>(
      xb, Wt_k, bk, nullptr, nullptr, nullptr, R1, nullptr);
  gemm_mfma<0><<<1536, 256, 0, stream>>>(
      xb, Wt_v, bv, nullptr, nullptr, nullptr, R2, nullptr);

  // dense 16x16 attention per (bt, m) -> node_new bf16 (over dead scores)
  attn_dense<<<12288, 256, 0, stream>>>(Qbuf, R1, R2, idxp, nnb);

  hipMemsetAsync(counts, 0, (size_t)NBT * NNODE * 4, stream);
  build_lists<<<768, 256, 0, stream>>>(idxp, lists, counts);
  gather_sum<<<49152, 256, 0, stream>>>(nnb, lists, counts, dictb);

  // value = dictb @ Wo + bo + (x+pos); LN fused -> vln bf16
  gemm_mfma<1><<<1536, 256, 0, stream>>>(
      dictb, Wt_o, bo, x, pos, nullptr, nullptr, vln);
  // h1 = relu(vln @ W1 + b1) bf16
  gemm_mfma<2><<<1536, 256, 0, stream>>>(
      vln, Wt_1, ffb1, nullptr, nullptr, nullptr, nullptr, h1);
  // out = LN(h1 @ W2 + b2 + vln) fp32
  gemm_mfma<3><<<1536, 256, 0, stream>>>(
      h1, Wt_2, ffb2, nullptr, nullptr, vln, outp, nullptr);
}

// Round 2
// 600.427 us; speedup vs baseline: 1.4473x; 1.1506x over previous
//
#include <hip/hip_runtime.h>
#include <math.h>

#define RTOT   196608   // B*T*N rows
#define NNODE  1024
#define NBT    192      // B*T

typedef __attribute__((ext_vector_type(8))) short short8;
typedef __attribute__((ext_vector_type(4))) float f32x4;

__device__ __forceinline__ unsigned short f2bf(float f) {
  unsigned u = __float_as_uint(f);
  return (unsigned short)((u + 0x7fffu + ((u >> 16) & 1u)) >> 16);
}
__device__ __forceinline__ float bf2f(unsigned short b) {
  return __uint_as_float(((unsigned)b) << 16);
}

// ---------------- prep kernels ----------------
__global__ __launch_bounds__(256) void pos_kernel(
    const float* __restrict__ eigvec, const float* __restrict__ eigval,
    float* __restrict__ pos) {
  int i = blockIdx.x * 256 + threadIdx.x;      // < 1024*128
  int d = i >> 10, n = i & 1023;
  pos[n * 128 + d] = eigvec[d * 1024 + n] * eigval[d];
}

// transpose + bf16-ify 6 [128][128] weights -> [w][col][k] bf16
__global__ __launch_bounds__(256) void prepw_kernel(
    const float* __restrict__ W0, const float* __restrict__ W1,
    const float* __restrict__ W2, const float* __restrict__ W3,
    const float* __restrict__ W4, const float* __restrict__ W5,
    unsigned short* __restrict__ out) {
  int i = blockIdx.x * 256 + threadIdx.x;      // < 6*16384
  int wsel = i >> 14, rem = i & 16383, c = rem >> 7, k = rem & 127;
  const float* W = (wsel == 0) ? W0 : (wsel == 1) ? W1 : (wsel == 2) ? W2
                 : (wsel == 3) ? W3 : (wsel == 4) ? W4 : W5;
  out[i] = f2bf(W[k * 128 + c]);
}

// folded score weights: Wcomb[k][m] = Wq[k]·embQ[m] + Wk[k]·embK[m]  (fp32)
//                       bcomb[m]    = bq·embQ[m] + bk·embK[m]
__global__ __launch_bounds__(256) void wcomb_kernel(
    const float* __restrict__ Wq, const float* __restrict__ Wk,
    const float* __restrict__ bq, const float* __restrict__ bk,
    const float* __restrict__ emb, float* __restrict__ Wcomb,
    float* __restrict__ bcomb) {
  int i = blockIdx.x * 256 + threadIdx.x;      // 8192 Wcomb + 64 bias
  if (i < 8192) {
    int k = i >> 6, m = i & 63;
    float s = 0.f;
    for (int d = 0; d < 128; ++d)
      s += Wq[k * 128 + d] * emb[m * 256 + d]
         + Wk[k * 128 + d] * emb[m * 256 + 128 + d];
    Wcomb[i] = s;
  } else if (i < 8256) {
    int m = i - 8192;
    float s = 0.f;
    for (int d = 0; d < 128; ++d)
      s += bq[d] * emb[m * 256 + d] + bk[d] * emb[m * 256 + 128 + d];
    bcomb[m] = s;
  }
}

// ---------------- generic 128-row-tile fp32 GEMM (score-critical path) ------
template<int NCOL, int KCHUNKS, int ADDPOS, int HASBIAS, int WRITEXB>
__global__ __launch_bounds__(256, 2) void gemm_k(
    const float* __restrict__ A1, const float* __restrict__ A2,
    const float* __restrict__ W, const float* __restrict__ bias,
    const float* __restrict__ pos, unsigned short* __restrict__ xb,
    float* __restrict__ out) {
  __shared__ float As[128 * 64];          // [m][k], 32 KB
  __shared__ float Ws[64 * NCOL];
  constexpr int JW = (NCOL == 128) ? 2 : 1;
  const int tid = threadIdx.x;
  const int tx = tid & 15, ty = tid >> 4;
  const int row0 = blockIdx.x * 128;

  float acc[8][4 * JW];
#pragma unroll
  for (int i = 0; i < 8; ++i)
#pragma unroll
    for (int j = 0; j < 4 * JW; ++j) acc[i][j] = 0.f;

  for (int kc = 0; kc < KCHUNKS; ++kc) {
    const int kt = kc * 64;
    const float* __restrict__ Asrc = (kt < 128) ? A1 : A2;
    const int kbase = kt & 127;
#pragma unroll
    for (int i = 0; i < 8; ++i) {
      int f = tid + 256 * i;
      int m = f >> 4;
      int k4 = (f & 15) << 2;
      int r = row0 + m;
      float4 a = *(const float4*)&Asrc[(size_t)r * 128 + kbase + k4];
      if constexpr (ADDPOS) {
        float4 p = *(const float4*)&pos[(r & 1023) * 128 + kbase + k4];
        a.x += p.x; a.y += p.y; a.z += p.z; a.w += p.w;
      }
      if constexpr (WRITEXB) {
        unsigned lo = (unsigned)f2bf(a.x) | ((unsigned)f2bf(a.y) << 16);
        unsigned hi = (unsigned)f2bf(a.z) | ((unsigned)f2bf(a.w) << 16);
        *(uint2*)&xb[(size_t)r * 128 + kbase + k4] = make_uint2(lo, hi);
      }
      *(float4*)&As[m * 64 + k4] = a;
    }
#pragma unroll
    for (int i = 0; i < NCOL / 16; ++i) {
      int f = tid + 256 * i;
      int kk = f / (NCOL / 4);
      int c4 = (f % (NCOL / 4)) << 2;
      *(float4*)&Ws[kk * NCOL + c4] =
          *(const float4*)&W[(size_t)(kt + kk) * NCOL + c4];
    }
    __syncthreads();
    for (int k4 = 0; k4 < 64; k4 += 4) {
      float a[8][4];
#pragma unroll
      for (int i = 0; i < 8; ++i)
        *(float4*)&a[i][0] = *(const float4*)&As[(ty * 8 + i) * 64 + k4];
#pragma unroll
      for (int kk = 0; kk < 4; ++kk) {
        float4 w0 = *(const float4*)&Ws[(k4 + kk) * NCOL + tx * 4];
        float4 w1;
        if constexpr (JW == 2)
          w1 = *(const float4*)&Ws[(k4 + kk) * NCOL + 64 + tx * 4];
#pragma unroll
        for (int i = 0; i < 8; ++i) {
          float av = a[i][kk];
          acc[i][0] = fmaf(av, w0.x, acc[i][0]);
          acc[i][1] = fmaf(av, w0.y, acc[i][1]);
          acc[i][2] = fmaf(av, w0.z, acc[i][2]);
          acc[i][3] = fmaf(av, w0.w, acc[i][3]);
          if constexpr (JW == 2) {
            acc[i][4] = fmaf(av, w1.x, acc[i][4]);
            acc[i][5] = fmaf(av, w1.y, acc[i][5]);
            acc[i][6] = fmaf(av, w1.z, acc[i][6]);
            acc[i][7] = fmaf(av, w1.w, acc[i][7]);
          }
        }
      }
    }
    __syncthreads();
  }
  float4 b0 = make_float4(0.f, 0.f, 0.f, 0.f);
  float4 b1 = make_float4(0.f, 0.f, 0.f, 0.f);
  if constexpr (HASBIAS) {
    b0 = *(const float4*)&bias[tx * 4];
    if constexpr (JW == 2) b1 = *(const float4*)&bias[64 + tx * 4];
  }
#pragma unroll
  for (int i = 0; i < 8; ++i) {
    const int r = row0 + ty * 8 + i;
    {
      float4 o = make_float4(acc[i][0] + b0.x, acc[i][1] + b0.y,
                             acc[i][2] + b0.z, acc[i][3] + b0.w);
      *(float4*)&out[(size_t)r * NCOL + tx * 4] = o;
    }
    if constexpr (JW == 2) {
      float4 o = make_float4(acc[i][4] + b1.x, acc[i][5] + b1.y,
                             acc[i][6] + b1.z, acc[i][7] + b1.w);
      *(float4*)&out[(size_t)r * NCOL + 64 + tx * 4] = o;
    }
  }
}

// ---------------- fused Q/K/V bf16 MFMA GEMM, 128x128 tile, K=128 -----------
// A fragments loaded once into registers; 3 weight sets looped.
__global__ __launch_bounds__(256, 2) void gemm_qkv(
    const unsigned short* __restrict__ A, const unsigned short* __restrict__ Wt,
    const float* __restrict__ bq, const float* __restrict__ bk,
    const float* __restrict__ bv,
    unsigned short* __restrict__ outq, unsigned short* __restrict__ outk,
    unsigned short* __restrict__ outv) {
  const int tid = threadIdx.x;
  const int w = tid >> 6, lane = tid & 63;
  const int wr = w >> 1, wc = w & 1;
  const int lhi = lane >> 4, llo = lane & 15;
  const int r0 = blockIdx.x * 128;

  short8 af[4][4];
#pragma unroll
  for (int i = 0; i < 4; ++i)
#pragma unroll
    for (int kq = 0; kq < 4; ++kq)
      af[i][kq] = *(const short8*)&A[(size_t)(r0 + wr * 64 + i * 16 + llo) * 128 +
                                     kq * 32 + lhi * 8];
#pragma unroll
  for (int s = 0; s < 3; ++s) {
    const unsigned short* __restrict__ Bt = Wt + s * 16384;
    const float* __restrict__ bias = (s == 0) ? bq : (s == 1) ? bk : bv;
    unsigned short* __restrict__ outb = (s == 0) ? outq : (s == 1) ? outk : outv;

    short8 bf[4][4];
#pragma unroll
    for (int j = 0; j < 4; ++j)
#pragma unroll
      for (int kq = 0; kq < 4; ++kq)
        bf[j][kq] = *(const short8*)&Bt[(size_t)(wc * 64 + j * 16 + llo) * 128 +
                                        kq * 32 + lhi * 8];
    f32x4 acc[4][4];
#pragma unroll
    for (int i = 0; i < 4; ++i)
#pragma unroll
      for (int j = 0; j < 4; ++j) acc[i][j] = (f32x4)(0.0f);
#pragma unroll
    for (int i = 0; i < 4; ++i)
#pragma unroll
      for (int kq = 0; kq < 4; ++kq)
#pragma unroll
        for (int j = 0; j < 4; ++j)
          acc[i][j] = __builtin_amdgcn_mfma_f32_16x16x32_bf16(
              af[i][kq], bf[j][kq], acc[i][j], 0, 0, 0);

    float bvals[4];
#pragma unroll
    for (int j = 0; j < 4; ++j) bvals[j] = bias[wc * 64 + j * 16 + llo];
#pragma unroll
    for (int i = 0; i < 4; ++i)
#pragma unroll
      for (int reg = 0; reg < 4; ++reg) {
        const int r = r0 + wr * 64 + i * 16 + lhi * 4 + reg;
#pragma unroll
        for (int j = 0; j < 4; ++j) {
          const int c = wc * 64 + j * 16 + llo;
          outb[(size_t)r * 128 + c] = f2bf(acc[i][j][reg] + bvals[j]);
        }
      }
  }
}

// ---------------- bf16 MFMA GEMM, 128x128 tile, K=128 -----------------------
// EPI: 1 = bias + (x+pos) resid + LN, bf16 out (Wo -> vln)
//      2 = bias + relu, bf16 out (FF1 -> h1)
//      3 = bias + bf16 resid + LN, fp32 out (FF2 -> final)
template<int EPI>
__global__ __launch_bounds__(256, 2) void gemm_mfma(
    const unsigned short* __restrict__ A, const unsigned short* __restrict__ Bt,
    const float* __restrict__ bias, const float* __restrict__ x,
    const float* __restrict__ pos, const unsigned short* __restrict__ resb,
    float* __restrict__ outf, unsigned short* __restrict__ outb) {
  __shared__ float lds_s[128][2];
  __shared__ float lds_q[128][2];
  const int tid = threadIdx.x;
  const int w = tid >> 6, lane = tid & 63;
  const int wr = w >> 1, wc = w & 1;
  const int lhi = lane >> 4, llo = lane & 15;
  const int r0 = blockIdx.x * 128;

  short8 bf[4][4];
#pragma unroll
  for (int j = 0; j < 4; ++j)
#pragma unroll
    for (int kq = 0; kq < 4; ++kq)
      bf[j][kq] = *(const short8*)&Bt[(size_t)(wc * 64 + j * 16 + llo) * 128 +
                                      kq * 32 + lhi * 8];
  f32x4 acc[4][4];
#pragma unroll
  for (int i = 0; i < 4; ++i)
#pragma unroll
    for (int j = 0; j < 4; ++j) acc[i][j] = (f32x4)(0.0f);

#pragma unroll
  for (int i = 0; i < 4; ++i) {
    short8 af[4];
#pragma unroll
    for (int kq = 0; kq < 4; ++kq)
      af[kq] = *(const short8*)&A[(size_t)(r0 + wr * 64 + i * 16 + llo) * 128 +
                                  kq * 32 + lhi * 8];
#pragma unroll
    for (int kq = 0; kq < 4; ++kq)
#pragma unroll
      for (int j = 0; j < 4; ++j)
        acc[i][j] = __builtin_amdgcn_mfma_f32_16x16x32_bf16(
            af[kq], bf[j][kq], acc[i][j], 0, 0, 0);
  }

  float bvals[4];
#pragma unroll
  for (int j = 0; j < 4; ++j) bvals[j] = bias[wc * 64 + j * 16 + llo];

  if constexpr (EPI == 1 || EPI == 3) {
#pragma unroll
    for (int i = 0; i < 4; ++i) {
#pragma unroll
      for (int reg = 0; reg < 4; ++reg) {
        const int rl = wr * 64 + i * 16 + lhi * 4 + reg;
        const int r = r0 + rl;
        float s = 0.f, q = 0.f;
#pragma unroll
        for (int j = 0; j < 4; ++j) {
          const int c = wc * 64 + j * 16 + llo;
          float vv = acc[i][j][reg] + bvals[j];
          if constexpr (EPI == 1)
            vv += x[(size_t)r * 128 + c] + pos[(r & 1023) * 128 + c];
          else
            vv += bf2f(resb[(size_t)r * 128 + c]);
          acc[i][j][reg] = vv;
          s += vv; q += vv * vv;
        }
#pragma unroll
        for (int m = 1; m < 16; m <<= 1) {
          s += __shfl_xor(s, m);
          q += __shfl_xor(q, m);
        }
        if (llo == 0) { lds_s[rl][wc] = s; lds_q[rl][wc] = q; }
      }
    }
    __syncthreads();
#pragma unroll
    for (int i = 0; i < 4; ++i) {
#pragma unroll
      for (int reg = 0; reg < 4; ++reg) {
        const int rl = wr * 64 + i * 16 + lhi * 4 + reg;
        const int r = r0 + rl;
        float s = lds_s[rl][0] + lds_s[rl][1];
        float q = lds_q[rl][0] + lds_q[rl][1];
        float mu = s * (1.f / 128.f);
        float rstd = rsqrtf(q * (1.f / 128.f) - mu * mu + 1e-5f);
#pragma unroll
        for (int j = 0; j < 4; ++j) {
          const int c = wc * 64 + j * 16 + llo;
          float vv = (acc[i][j][reg] - mu) * rstd;
          if constexpr (EPI == 1)
            outb[(size_t)r * 128 + c] = f2bf(vv);
          else
            outf[(size_t)r * 128 + c] = vv;
        }
      }
    }
  } else {
#pragma unroll
    for (int i = 0; i < 4; ++i)
#pragma unroll
      for (int reg = 0; reg < 4; ++reg) {
        const int rl = wr * 64 + i * 16 + lhi * 4 + reg;
        const int r = r0 + rl;
#pragma unroll
        for (int j = 0; j < 4; ++j) {
          const int c = wc * 64 + j * 16 + llo;
          float vv = acc[i][j][reg] + bvals[j];
          if constexpr (EPI == 2) {
            vv = fmaxf(vv, 0.f);
            outb[(size_t)r * 128 + c] = f2bf(vv);
          } else {
            outf[(size_t)r * 128 + c] = vv;
          }
        }
      }
  }
}

// ---------------- top-16 per (bt, m): bitonic merge-tree on values ----------
// Set semantics: downstream (softmax over set + scatter-add) is invariant to
// slot order, so we find the 16th-largest value t* via a value-only bitonic
// top-16 merge across 64 lanes, then collect indices with >= t* + LDS counter.
__global__ __launch_bounds__(256) void topk_kernel(
    const float* __restrict__ S, int* __restrict__ idx_out) {
  __shared__ float sc[8 * 1088];   // 8 rows, 64 chunks of 17 (16 data + 1 pad)
  __shared__ int cnt[8];
  const int tid = threadIdx.x;
  const int bt = blockIdx.x >> 3, mg = blockIdx.x & 7;
  if (tid < 8) cnt[tid] = 0;
#pragma unroll
  for (int u = 0; u < 8; ++u) {
    int f = tid + 256 * u;         // < 2048
    int n = f >> 1, half = f & 1;
    float4 v = *(const float4*)&S[((size_t)bt * 1024 + n) * 64 + mg * 8 + half * 4];
    int p = (n >> 4) * 17 + (n & 15);
    sc[(half * 4 + 0) * 1088 + p] = v.x;
    sc[(half * 4 + 1) * 1088 + p] = v.y;
    sc[(half * 4 + 2) * 1088 + p] = v.z;
    sc[(half * 4 + 3) * 1088 + p] = v.w;
  }
  __syncthreads();
  const int lane = tid & 63, w = tid >> 6;
  for (int h2 = 0; h2 < 2; ++h2) {
    const int ml = w * 2 + h2;
    float ov[16], r[16];
#pragma unroll
    for (int j = 0; j < 16; ++j) {
      float t = sc[ml * 1088 + lane * 17 + j];
      ov[j] = t; r[j] = t;
    }
    // in-register bitonic sort, ascending
#pragma unroll
    for (int k = 2; k <= 16; k <<= 1) {
#pragma unroll
      for (int d = k >> 1; d >= 1; d >>= 1) {
#pragma unroll
        for (int i = 0; i < 16; ++i) {
          int j = i ^ d;
          if (j > i) {
            bool up = ((i & k) == 0);
            float a = r[i], b = r[j];
            float mn = fminf(a, b), mx = fmaxf(a, b);
            r[i] = up ? mn : mx;
            r[j] = up ? mx : mn;
          }
        }
      }
    }
    // 6-level butterfly merge: keep top-16 of union, re-sorted ascending
#pragma unroll
    for (int md = 1; md < 64; md <<= 1) {
      float c[16];
#pragma unroll
      for (int i = 0; i < 16; ++i)
        c[i] = fmaxf(r[i], __shfl_xor(r[15 - i], md));
#pragma unroll
      for (int d = 8; d >= 1; d >>= 1) {
#pragma unroll
        for (int i = 0; i < 16; ++i) {
          int j = i ^ d;
          if (j > i) {
            float a = c[i], b = c[j];
            c[i] = fminf(a, b);
            c[j] = fmaxf(a, b);
          }
        }
      }
#pragma unroll
      for (int i = 0; i < 16; ++i) r[i] = c[i];
    }
    const float tstar = r[0];      // 16th largest
    const int outbase = (bt * 64 + mg * 8 + ml) << 4;
#pragma unroll
    for (int j = 0; j < 16; ++j) {
      if (ov[j] >= tstar) {
        int s = atomicAdd(&cnt[ml], 1);
        if (s < 16) idx_out[outbase + s] = lane * 16 + j;
      }
    }
  }
}

// ---------------- 16x16 attention over bf16 Q/K/V, dense bf16 output --------
__global__ __launch_bounds__(256) void attn_dense(
    const unsigned short* __restrict__ Q, const unsigned short* __restrict__ K,
    const unsigned short* __restrict__ V, const int* __restrict__ idx,
    unsigned short* __restrict__ node_new) {
  __shared__ float sQ[16 * 132], sK[16 * 132], sV[16 * 132];
  __shared__ float sP[16 * 16];
  __shared__ int sidx[16];
  const int tid = threadIdx.x;
  const int bt = blockIdx.x >> 6, m = blockIdx.x & 63;
  if (tid < 16) sidx[tid] = idx[((bt * 64 + m) << 4) + tid];
  __syncthreads();
  const size_t base = (size_t)bt * 1024 * 128;
#pragma unroll
  for (int u = 0; u < 3; ++u) {
    int f = tid + 256 * u;         // < 768
    int mat = f >> 8;
    int rem = f & 255;
    int r = rem >> 4;
    int c8 = (rem & 15) << 3;
    const unsigned short* src = (mat == 0) ? Q : (mat == 1) ? K : V;
    float* dst = (mat == 0) ? sQ : (mat == 1) ? sK : sV;
    uint4 raw = *(const uint4*)&src[base + (size_t)sidx[r] * 128 + c8];
    float4 f0 = make_float4(bf2f(raw.x & 0xffff), bf2f(raw.x >> 16),
                            bf2f(raw.y & 0xffff), bf2f(raw.y >> 16));
    float4 f1 = make_float4(bf2f(raw.z & 0xffff), bf2f(raw.z >> 16),
                            bf2f(raw.w & 0xffff), bf2f(raw.w >> 16));
    *(float4*)&dst[r * 132 + c8] = f0;
    *(float4*)&dst[r * 132 + c8 + 4] = f1;
  }
  __syncthreads();
  const int kk = tid >> 4, jj = tid & 15;
  float s = 0.f;
#pragma unroll
  for (int c4 = 0; c4 < 128; c4 += 4) {
    float4 q = *(const float4*)&sQ[kk * 132 + c4];
    float4 kv = *(const float4*)&sK[jj * 132 + c4];
    s = fmaf(q.x, kv.x, s); s = fmaf(q.y, kv.y, s);
    s = fmaf(q.z, kv.z, s); s = fmaf(q.w, kv.w, s);
  }
  s *= 0.08838834764831845f;       // 1/sqrt(128)
  float mx = s;
#pragma unroll
  for (int off = 8; off >= 1; off >>= 1) mx = fmaxf(mx, __shfl_xor(mx, off, 16));
  float e = expf(s - mx);
  float sum = e;
#pragma unroll
  for (int off = 8; off >= 1; off >>= 1) sum += __shfl_xor(sum, off, 16);
  sP[kk * 16 + jj] = e / sum;
  __syncthreads();
  const int dc = tid & 15;
  const int d0 = dc * 8;
  float o[8] = {0.f, 0.f, 0.f, 0.f, 0.f, 0.f, 0.f, 0.f};
#pragma unroll
  for (int j = 0; j < 16; ++j) {
    float p = sP[kk * 16 + j];
    float4 v0 = *(const float4*)&sV[j * 132 + d0];
    float4 v1 = *(const float4*)&sV[j * 132 + d0 + 4];
    o[0] = fmaf(p, v0.x, o[0]); o[1] = fmaf(p, v0.y, o[1]);
    o[2] = fmaf(p, v0.z, o[2]); o[3] = fmaf(p, v0.w, o[3]);
    o[4] = fmaf(p, v1.x, o[4]); o[5] = fmaf(p, v1.y, o[5]);
    o[6] = fmaf(p, v1.z, o[6]); o[7] = fmaf(p, v1.w, o[7]);
  }
  unsigned short* orow = node_new + base + (size_t)(m * 16 + kk) * 128 + d0;
  uint4 st;
  st.x = (unsigned)f2bf(o[0]) | ((unsigned)f2bf(o[1]) << 16);
  st.y = (unsigned)f2bf(o[2]) | ((unsigned)f2bf(o[3]) << 16);
  st.z = (unsigned)f2bf(o[4]) | ((unsigned)f2bf(o[5]) << 16);
  st.w = (unsigned)f2bf(o[6]) | ((unsigned)f2bf(o[7]) << 16);
  *(uint4*)orow = st;
}

// ---------------- invert idx_flat into per-node hit lists ----------------
__global__ __launch_bounds__(256) void build_lists(
    const int* __restrict__ idx, int* __restrict__ lists,
    int* __restrict__ counts) {
  int i = blockIdx.x * 256 + threadIdx.x;      // < 192*1024
  int bt = i >> 10, j = i & 1023;
  int n = idx[i];
  int slot = atomicAdd(&counts[bt * 1024 + n], 1);
  lists[(size_t)(bt * 1024 + n) * 64 + slot] = j;
}

// ---------------- gather-sum: dictb[bt][n] = bf16(sum(rows)/cnt) ------------
__global__ __launch_bounds__(256) void gather_sum(
    const unsigned short* __restrict__ node_new, const int* __restrict__ lists,
    const int* __restrict__ counts, unsigned short* __restrict__ outb) {
  const int lane = threadIdx.x & 63;
  const int row = blockIdx.x * 4 + (threadIdx.x >> 6);   // bt*1024+n
  const int cnt = counts[row];
  const int bt = row >> 10;
  const float inv = 1.0f / ((float)cnt + 1e-14f);
  const int* lp = lists + (size_t)row * 64;
  float ax = 0.f, ay = 0.f;
  for (int j = 0; j < cnt; ++j) {
    int src = lp[j];
    unsigned u = *(const unsigned*)&node_new[((size_t)bt * 1024 + src) * 128 + lane * 2];
    ax += bf2f(u & 0xffff); ay += bf2f(u >> 16);
  }
  ax *= inv; ay *= inv;
  unsigned pk = (unsigned)f2bf(ax) | ((unsigned)f2bf(ay) << 16);
  *(unsigned*)&outb[(size_t)row * 128 + lane * 2] = pk;
}

// ---------------- launch ----------------
extern "C" void kernel_launch(void* const* d_in, const int* in_sizes, int n_in,
                              void* d_out, int out_size, void* d_ws, size_t ws_size,
                              hipStream_t stream) {
  const float* x      = (const float*)d_in[0];
  const float* eigvec = (const float*)d_in[1];
  const float* eigval = (const float*)d_in[2];
  const float* Wq     = (const float*)d_in[3];
  const float* bq     = (const float*)d_in[4];
  const float* Wk     = (const float*)d_in[5];
  const float* bk     = (const float*)d_in[6];
  const float* Wv     = (const float*)d_in[7];
  const float* bv     = (const float*)d_in[8];
  const float* Wo     = (const float*)d_in[9];
  const float* bo     = (const float*)d_in[10];
  const float* nemb   = (const float*)d_in[11];
  const float* ffW1   = (const float*)d_in[12];
  const float* ffb1   = (const float*)d_in[13];
  const float* ffW2   = (const float*)d_in[14];
  const float* ffb2   = (const float*)d_in[15];
  float* outp = (float*)d_out;

  char* ws = (char*)d_ws;
  float*          pos    = (float*)(ws + 0);                  // 512 KB
  int*            idxp   = (int*)  (ws + 524288);             // 768 KB
  int*            counts = (int*)  (ws + 1310720);            // 768 KB
  // Wcomb/bcomb overlay counts: dead before counts memset (stream-ordered)
  float*          Wcomb  = (float*)(ws + 1310720);            // 32 KB
  float*          bcomb  = (float*)(ws + 1343488);            // 256 B
  unsigned short* Wtall  = (unsigned short*)(ws + 2097152);   // 192 KB (6 W^T bf16)
  unsigned short* xb     = (unsigned short*)(ws + 2293760);   // 48 MB: bf16(x+pos) -> vln
  unsigned short* Kb     = (unsigned short*)(ws + 52625408);  // 48 MB: K bf16 -> h1
  unsigned short* Vb     = (unsigned short*)(ws + 102957056); // 48 MB: V bf16 -> lists
  float*          Sbuf   = (float*)(ws + 153288704);          // 48 MB: scores -> node_new
  unsigned short* Wt_o = Wtall + 49152;
  unsigned short* Wt_1 = Wtall + 65536;
  unsigned short* Wt_2 = Wtall + 81920;
  unsigned short* vln  = xb;                    // reuses xb after QKV
  unsigned short* h1   = Kb;                    // reuses K after attn
  int*            lists = (int*)Vb;             // reuses V after attn
  unsigned short* nnb  = (unsigned short*)Sbuf; // node_new bf16, after topk
  unsigned short* Qb   = (unsigned short*)d_out; // Q bf16 in d_out until attn done
  unsigned short* dictb = (unsigned short*)d_out; // after gather (Q dead)

  pos_kernel<<<512, 256, 0, stream>>>(eigvec, eigval, pos);
  prepw_kernel<<<384, 256, 0, stream>>>(Wq, Wk, Wv, Wo, ffW1, ffW2, Wtall);
  wcomb_kernel<<<33, 256, 0, stream>>>(Wq, Wk, bq, bk, nemb, Wcomb, bcomb);

  // scores = (x+pos) @ Wcomb + bcomb  (fp32, top-k-critical path)
  // also emits xb = bf16(x+pos) for the MFMA GEMMs
  gemm_k<64, 2, 1, 1, 1><<<1536, 256, 0, stream>>>(
      x, nullptr, Wcomb, bcomb, pos, xb, Sbuf);
  topk_kernel<<<1536, 256, 0, stream>>>(Sbuf, idxp);

  // fused Q/K/V via bf16 MFMA, bf16 out — feed the 16x16 attention only
  gemm_qkv<<<1536, 256, 0, stream>>>(xb, Wtall, bq, bk, bv, Qb, Kb, Vb);

  // dense 16x16 attention per (bt, m) -> node_new bf16 (over dead scores)
  attn_dense<<<12288, 256, 0, stream>>>(Qb, Kb, Vb, idxp, nnb);

  hipMemsetAsync(counts, 0, (size_t)NBT * NNODE * 4, stream);
  build_lists<<<768, 256, 0, stream>>>(idxp, lists, counts);
  gather_sum<<<49152, 256, 0, stream>>>(nnb, lists, counts, dictb);

  // value = dictb @ Wo + bo + (x+pos); LN fused -> vln bf16
  gemm_mfma<1><<<1536, 256, 0, stream>>>(
      dictb, Wt_o, bo, x, pos, nullptr, nullptr, vln);
  // h1 = relu(vln @ W1 + b1) bf16
  gemm_mfma<2><<<1536, 256, 0, stream>>>(
      vln, Wt_1, ffb1, nullptr, nullptr, nullptr, nullptr, h1);
  // out = LN(h1 @ W2 + b2 + vln) fp32
  gemm_mfma<3><<<1536, 256, 0, stream>>>(
      h1, Wt_2, ffb2, nullptr, nullptr, vln, outp, nullptr);
}